// Round 16
// baseline (123.999 us; speedup 1.0000x reference)
//
#include <hip/hip_runtime.h>
#include <hip/hip_fp16.h>
#include <math.h>

#define N_NODES 100000
#define N_EDGES 1600000
#define NBUCK   1563          // ceil(100000/64) buckets of 64 dst nodes
#define NBUCK_P 1568          // padded row length for hist tables
#define NB_HIST 256           // hist blocks (slice 6250)
#define NB_BIN  256           // bin blocks (slice 6250, same rows as hist)
#define DCAP    1536          // fixed dump capacity per bucket (max ~1136 + 12 sigma)

// ws layout (bytes)
#define OFF_BTOT   0x1000u     // int[NBUCK_P] bucket totals (record count m)
#define OFF_HS     0x780000u   // fp8[N_NODES*128] (12.8 MB)
#define OFF_WT     0x2100000u  // __half[128*128] fp16 W1^T (32 KB)
#define OFF_WLT    0x2110000u  // __half[64*128]  fp16 linW^T, class-padded (16 KB)
#define OFF_GHIST  0x3980000u  // int[NB_HIST*NBUCK_P]  (1.6 MB)
#define OFF_GCHOFF 0x3B10000u  // int[NB_BIN*NBUCK_P]   (1.6 MB)
#define OFF_DUMP   0x3CA0000u  // int[NBUCK*DCAP] packed (9.6 MB)

typedef _Float16 half8_t __attribute__((ext_vector_type(8)));
typedef float f32x2_t __attribute__((ext_vector_type(2)));
typedef float f32x4_t __attribute__((ext_vector_type(4)));
typedef float f32x16_t __attribute__((ext_vector_type(16)));

// blocks [0,255]: per-block bucket histogram of dst (inline dtype detect).
// blocks [256,271]: W1 (f32 [128k][128n]) -> Wt fp16 [128n][128k].
// block  272:       linW (f32 [128k][40c]) -> WlT fp16 [64c][128k] (pad c>=40 = 0).
__global__ __launch_bounds__(256) void k_hist(const int* __restrict__ p32,
                                              int* __restrict__ G_hist,
                                              const float* __restrict__ W,
                                              __half* __restrict__ Wt,
                                              const float* __restrict__ linW,
                                              __half* __restrict__ WlT) {
  const int t = threadIdx.x;
  if (blockIdx.x == NB_HIST + 16) {  // ---- linW transpose ----
    __shared__ float buf[5120];
#pragma unroll
    for (int i = 0; i < 5; ++i) {
      int lin = i * 256 + t;
      ((float4*)buf)[lin] = ((const float4*)linW)[lin];
    }
    __syncthreads();
#pragma unroll
    for (int i = 0; i < 4; ++i) {
      int lin = i * 256 + t;  // 1024 int4s = 64 rows x 16
      int c = lin >> 4, kb = lin & 15;
      union { __half h[8]; int4 v; } u;
#pragma unroll
      for (int q = 0; q < 8; ++q)
        u.h[q] = (c < 40) ? __float2half(buf[(kb * 8 + q) * 40 + c])
                          : __float2half(0.f);
      *(int4*)&WlT[(size_t)c * 128 + kb * 8] = u.v;
    }
    return;
  }
  if (blockIdx.x >= NB_HIST) {  // ---- W1 transpose ----
    __shared__ float buf1[1024];
    const int b = blockIdx.x - NB_HIST;
    float4 v = ((const float4*)(W + (size_t)b * 1024))[t];
    *(float4*)&buf1[t * 4] = v;
    __syncthreads();
    if (t < 128) {
      union { __half h[8]; int4 v; } u;
#pragma unroll
      for (int k = 0; k < 8; ++k) u.h[k] = __float2half(buf1[k * 128 + t]);
      *(int4*)&Wt[(size_t)t * 128 + b * 8] = u.v;
    }
    return;
  }
  __shared__ int hist[NBUCK];
  __shared__ int nz;
  if (t == 0) nz = 0;
  for (int i = t; i < NBUCK; i += 256) hist[i] = 0;
  __syncthreads();
  if (p32[2 * t + 1] != 0) atomicAdd(&nz, 1);
  __syncthreads();
  const int s = (nz == 0) ? 1 : 0;  // 1 => int64 (stride 2)
  const int base = blockIdx.x * 6250;
  for (int i = 0; i < 25; ++i) {
    int e = base + i * 256 + t;
    if (e < base + 6250) {
      int c = p32[((size_t)(N_EDGES + e)) << s];
      atomicAdd(&hist[c >> 6], 1);
    }
  }
  __syncthreads();
  for (int i = t; i < NBUCK; i += 256) G_hist[blockIdx.x * NBUCK_P + i] = hist[i];
}

// per bucket: scan 256 exact chunk sizes -> per-binblock offsets + total (= m)
__global__ __launch_bounds__(256) void k_bucket_scan(const int* __restrict__ G_hist,
                                                     int* __restrict__ G_choff,
                                                     int* __restrict__ btot) {
  __shared__ int wsum[4];
  const int t = threadIdx.x;
  const int b = blockIdx.x;
  const int c = G_hist[t * NBUCK_P + b];
  int sv = c;
  const int lane = t & 63;
  for (int d = 1; d < 64; d <<= 1) {
    int a = __shfl_up(sv, d);
    if (lane >= d) sv += a;
  }
  if (lane == 63) wsum[t >> 6] = sv;
  __syncthreads();
  int o = 0;
  for (int w2 = 0; w2 < (t >> 6); ++w2) o += wsum[w2];
  G_choff[t * NBUCK_P + b] = o + sv - c;  // exclusive offset within bucket
  if (t == 255) btot[b] = o + sv;
}

// place packed (src<<6|ldst) records into block-private chunks at fixed bases
__global__ __launch_bounds__(512) void k_bin(const int* __restrict__ p32,
                                             const int* __restrict__ G_choff,
                                             int* __restrict__ dump) {
  __shared__ int gb[NBUCK];
  __shared__ int cur[NBUCK];
  __shared__ int nz;
  const int t = threadIdx.x;
  const int blk = blockIdx.x;
  if (t == 0) nz = 0;
  for (int i = t; i < NBUCK; i += 512) {
    gb[i] = i * DCAP + G_choff[blk * NBUCK_P + i];
    cur[i] = 0;
  }
  __syncthreads();
  if (t < 256 && p32[2 * t + 1] != 0) atomicAdd(&nz, 1);
  __syncthreads();
  const int s = (nz == 0) ? 1 : 0;
  const int base = blk * 6250;
  for (int i = 0; i < 13; ++i) {
    int e = base + i * 512 + t;
    if (e < base + 6250) {
      int r = p32[((size_t)e) << s];
      int c = p32[((size_t)(N_EDGES + e)) << s];
      int bk = c >> 6;
      int p = atomicAdd(&cur[bk], 1);
      dump[gb[bk] + p] = (r << 6) | (c & 63);
    }
  }
}

// hs[n] = fp8_e4m3( rsqrt(deg[n]+1) * (x @ W1)[n] )  via MFMA f16.
// 256 threads, NO weight/x LDS: A-fragments are 8-contiguous-k slices of x rows
// (loaded f32 direct, cvt to f16); B-fragments stream from global Wt (L2-hot).
__global__ __launch_bounds__(256, 6) void k_gemm1(
    const float* __restrict__ x, const __half* __restrict__ Wt,
    const int* __restrict__ dump, const int* __restrict__ btot,
    unsigned char* __restrict__ hs8) {
  __shared__ int c_s[64];
  const int t = threadIdx.x;
  const int b = blockIdx.x;
  const int row0 = b * 64;
  if (t < 64) c_s[t] = 0;
  __syncthreads();
  // degree pass over this bucket's dump chunk
  {
    const int rb = b * DCAP;
    const int m = btot[b];
    for (int j = t; j < m; j += 256) atomicAdd(&c_s[dump[rb + j] & 63], 1);
  }
  // A fragments: wave w owns rows w*16..w*16+15; lane (r,g): row w*16+r, k=ks*32+g*8
  const int w = t >> 6, l = t & 63;
  const int r = l & 15, g = l >> 4;
  const int arow = row0 + w * 16 + r;
  half8_t af[4];
#pragma unroll
  for (int ks = 0; ks < 4; ++ks) {
    float4 v0 = make_float4(0.f, 0.f, 0.f, 0.f), v1 = v0;
    if (arow < N_NODES) {
      const float* xp = x + (size_t)arow * 128 + ks * 32 + g * 8;
      v0 = *(const float4*)xp;
      v1 = *(const float4*)(xp + 4);
    }
    half8_t h;
    h[0] = (_Float16)v0.x; h[1] = (_Float16)v0.y;
    h[2] = (_Float16)v0.z; h[3] = (_Float16)v0.w;
    h[4] = (_Float16)v1.x; h[5] = (_Float16)v1.y;
    h[6] = (_Float16)v1.z; h[7] = (_Float16)v1.w;
    af[ks] = h;
  }
  __syncthreads();  // c_s ready

  const int lbase = w * 16 + g * 4;
  const int rbase = row0 + lbase;
  float dv[4];
#pragma unroll
  for (int j = 0; j < 4; ++j)
    dv[j] = rsqrtf((float)c_s[lbase + j] + 1.0f);

#pragma unroll
  for (int ct = 0; ct < 8; ++ct) {
    f32x4_t acc = {0.f, 0.f, 0.f, 0.f};
    const __half* bp = Wt + (size_t)(ct * 16 + r) * 128 + g * 8;
#pragma unroll
    for (int ks = 0; ks < 4; ++ks) {
      half8_t bf = *(const half8_t*)(bp + ks * 32);
      acc = __builtin_amdgcn_mfma_f32_16x16x32_f16(af[ks], bf, acc, 0, 0, 0);
    }
#pragma unroll
    for (int j = 0; j < 4; ++j) {
      int rr = rbase + j;
      if (rr < N_NODES) {
        unsigned int pk =
            __builtin_amdgcn_cvt_pk_fp8_f32(acc[j] * dv[j], 0.f, 0u, false);
        hs8[(size_t)rr * 128 + ct * 16 + r] = (unsigned char)(pk & 0xffu);
      }
    }
  }
}

// fully fused per bucket (64 nodes, 256 threads):
// local deg + CSR placement -> fp8 gather-aggregate -> relu'd fp16 rows in LDS ->
// MFMA Linear (WlT from global, L2-hot) -> log_softmax -> out.
__global__ __launch_bounds__(256, 6) void k_aggfin(
    const unsigned char* __restrict__ hs8, const int* __restrict__ dump,
    const int* __restrict__ btot, const float* __restrict__ b1,
    const __half* __restrict__ WlT, const float* __restrict__ linb,
    float* __restrict__ out) {
  __shared__ int stage[4352];          // 17408 B; alias vs[64][136] f16, outbuf[64][68] f32
  __shared__ float lb_s[64];
  __shared__ int cnt_s[64];
  __shared__ int off_s[64];
  __shared__ int cur_s[64];
  _Float16* vs = (_Float16*)stage;
  float* outbuf = (float*)stage;

  const int t = threadIdx.x;
  const int b = blockIdx.x;
  const int n0 = b << 6;
  if (t < 64) cnt_s[t] = 0;
  if (t >= 64 && t < 128) lb_s[t - 64] = (t - 64 < 40) ? linb[t - 64] : 0.f;
  __syncthreads();

  const int rb = b * DCAP;
  const int m = btot[b];
  // pass 1: degree count
  for (int j = t; j < m; j += 256) atomicAdd(&cnt_s[dump[rb + j] & 63], 1);
  __syncthreads();
  if (t < 64) {
    int v = cnt_s[t];
    int sv = v;
    for (int d = 1; d < 64; d <<= 1) {
      int u = __shfl_up(sv, d);
      if (t >= d) sv += u;
    }
    off_s[t] = sv - v;
    cur_s[t] = sv - v;
  }
  __syncthreads();
  // pass 2: place src indices grouped by dst
  for (int j = t; j < m; j += 256) {
    int rec = dump[rb + j];
    int p = atomicAdd(&cur_s[rec & 63], 1);
    stage[p] = rec >> 6;
  }
  __syncthreads();

  // gather-aggregate: half-wave hw (0..7) handles nodes hw, hw+8, ..., hw+56.
  // Each lane owns cols lane*4..lane*4+3 (4 fp8 bytes = 1 dword per row).
  const int hw = t >> 5, lane = t & 31;
  uint2 res[8];
#pragma unroll
  for (int mi = 0; mi < 8; ++mi) {
    res[mi] = make_uint2(0u, 0u);
    const int i = hw + mi * 8;
    const int n = n0 + i;
    if (n >= N_NODES) continue;
    f32x4_t sum;
    {
      unsigned int raw = *(const unsigned int*)(hs8 + (size_t)n * 128 + lane * 4);
      f32x2_t lo = __builtin_amdgcn_cvt_pk_f32_fp8(raw, false);
      f32x2_t hi = __builtin_amdgcn_cvt_pk_f32_fp8(raw, true);
      sum[0] = lo[0]; sum[1] = lo[1]; sum[2] = hi[0]; sum[3] = hi[1];  // self-loop
    }
    int j = off_s[i];
    const int e0 = off_s[i] + cnt_s[i];
    for (; j + 8 <= e0; j += 8) {
      unsigned int r[8];
#pragma unroll
      for (int q = 0; q < 8; ++q) {
        int src = stage[j + q];
        r[q] = *(const unsigned int*)(hs8 + (size_t)src * 128 + lane * 4);
      }
#pragma unroll
      for (int q = 0; q < 8; ++q) {
        f32x2_t lo = __builtin_amdgcn_cvt_pk_f32_fp8(r[q], false);
        f32x2_t hi = __builtin_amdgcn_cvt_pk_f32_fp8(r[q], true);
        f32x4_t v; v[0] = lo[0]; v[1] = lo[1]; v[2] = hi[0]; v[3] = hi[1];
        sum += v;
      }
    }
    if (j + 4 <= e0) {
      unsigned int r[4];
#pragma unroll
      for (int q = 0; q < 4; ++q) {
        int src = stage[j + q];
        r[q] = *(const unsigned int*)(hs8 + (size_t)src * 128 + lane * 4);
      }
#pragma unroll
      for (int q = 0; q < 4; ++q) {
        f32x2_t lo = __builtin_amdgcn_cvt_pk_f32_fp8(r[q], false);
        f32x2_t hi = __builtin_amdgcn_cvt_pk_f32_fp8(r[q], true);
        f32x4_t v; v[0] = lo[0]; v[1] = lo[1]; v[2] = hi[0]; v[3] = hi[1];
        sum += v;
      }
      j += 4;
    }
    for (; j < e0; ++j) {
      int src = stage[j];
      unsigned int raw = *(const unsigned int*)(hs8 + (size_t)src * 128 + lane * 4);
      f32x2_t lo = __builtin_amdgcn_cvt_pk_f32_fp8(raw, false);
      f32x2_t hi = __builtin_amdgcn_cvt_pk_f32_fp8(raw, true);
      f32x4_t v; v[0] = lo[0]; v[1] = lo[1]; v[2] = hi[0]; v[3] = hi[1];
      sum += v;
    }
    float d = rsqrtf((float)cnt_s[i] + 1.0f);
    float4 bb = *(const float4*)(b1 + lane * 4);
    union { __half2 h[2]; uint2 v; } u;
    u.h[0] = __floats2half2_rn(fmaxf(fmaf(d, sum[0], bb.x), 0.f),
                               fmaxf(fmaf(d, sum[1], bb.y), 0.f));
    u.h[1] = __floats2half2_rn(fmaxf(fmaf(d, sum[2], bb.z), 0.f),
                               fmaxf(fmaf(d, sum[3], bb.w), 0.f));
    res[mi] = u.v;
  }
  __syncthreads();  // stage (records) dead -> reuse as vs
#pragma unroll
  for (int mi = 0; mi < 8; ++mi) {
    const int i = hw + mi * 8;
    *(uint2*)&vs[i * 136 + lane * 4] = res[mi];
  }
  __syncthreads();

  // MFMA Linear: vs[64x128] @ WlT^T -> logits 64x64 (cols>=40 ignored).
  // 4 waves = 2x2 tiles of 32x32; B-fragments straight from global WlT (L2-hot).
  const int wv = t >> 6, l64 = t & 63;
  const int rowt = wv >> 1, colt = wv & 1;
  const int rw = l64 & 31, kg = l64 >> 5;  // kg in {0,1}
  f32x16_t C = {};
  {
    const _Float16* ap = &vs[(rowt * 32 + rw) * 136 + kg * 8];
    const __half* bp = WlT + (size_t)(colt * 32 + rw) * 128 + kg * 8;
#pragma unroll
    for (int ks = 0; ks < 8; ++ks) {
      half8_t af = *(const half8_t*)&ap[ks * 16];
      half8_t bf = *(const half8_t*)(bp + ks * 16);
      C = __builtin_amdgcn_mfma_f32_32x32x16_f16(af, bf, C, 0, 0, 0);
    }
  }
  const int colg = colt * 32 + rw;
  const float lbv = lb_s[colg];
  __syncthreads();  // all vs reads done -> safe to overwrite as outbuf
  if (colg < 40) {
    const int hi = kg;
#pragma unroll
    for (int q = 0; q < 16; ++q) {
      int row = (q & 3) + 8 * (q >> 2) + 4 * hi;  // C/D layout (m74/m101)
      outbuf[(rowt * 32 + row) * 68 + colg] = C[q] + lbv;
    }
  }
  __syncthreads();

  // softmax: node = t>>2 (64 nodes), 10 classes per 4-lane slot
  const int node = t >> 2;
  const int cg = (t & 3) * 10;
  const int n = n0 + node;
  float lg[10];
#pragma unroll
  for (int j = 0; j < 10; ++j) lg[j] = outbuf[node * 68 + cg + j];
  float mx = lg[0];
#pragma unroll
  for (int j = 1; j < 10; ++j) mx = fmaxf(mx, lg[j]);
  mx = fmaxf(mx, __shfl_xor(mx, 1));
  mx = fmaxf(mx, __shfl_xor(mx, 2));
  float ssum = 0.f;
#pragma unroll
  for (int j = 0; j < 10; ++j) ssum += expf(lg[j] - mx);
  ssum += __shfl_xor(ssum, 1);
  ssum += __shfl_xor(ssum, 2);
  float lse = mx + logf(ssum);
  if (n < N_NODES) {
#pragma unroll
    for (int j = 0; j < 10; ++j) out[(size_t)n * 40 + cg + j] = lg[j] - lse;
  }
}

extern "C" void kernel_launch(void* const* d_in, const int* in_sizes, int n_in,
                              void* d_out, int out_size, void* d_ws, size_t ws_size,
                              hipStream_t stream) {
  const float* x    = (const float*)d_in[0];
  const int*   ei   = (const int*)d_in[1];
  const float* W1   = (const float*)d_in[2];
  const float* b1   = (const float*)d_in[3];
  const float* linW = (const float*)d_in[4];
  const float* linb = (const float*)d_in[5];
  float* out = (float*)d_out;
  char* ws = (char*)d_ws;

  int*           btot   = (int*)(ws + OFF_BTOT);
  unsigned char* hs8    = (unsigned char*)(ws + OFF_HS);
  __half*        Wt     = (__half*)(ws + OFF_WT);
  __half*        WlT    = (__half*)(ws + OFF_WLT);
  int*           ghist  = (int*)(ws + OFF_GHIST);
  int*           gchoff = (int*)(ws + OFF_GCHOFF);
  int*           dump   = (int*)(ws + OFF_DUMP);

  k_hist<<<NB_HIST + 17, 256, 0, stream>>>(ei, ghist, W1, Wt, linW, WlT);
  k_bucket_scan<<<NBUCK, 256, 0, stream>>>(ghist, gchoff, btot);
  k_bin<<<NB_BIN, 512, 0, stream>>>(ei, gchoff, dump);
  k_gemm1<<<NBUCK, 256, 0, stream>>>(x, Wt, dump, btot, hs8);
  k_aggfin<<<NBUCK, 256, 0, stream>>>(hs8, dump, btot, b1, WlT, linb, out);
}

// Round 17
// 104.678 us; speedup vs baseline: 1.1846x; 1.1846x over previous
//
#include <hip/hip_runtime.h>
#include <hip/hip_fp16.h>
#include <math.h>

#define N_NODES 100000
#define N_EDGES 1600000
#define NBUCK   1563          // ceil(100000/64) buckets of 64 dst nodes
#define NBUCK_P 1568          // padded row length for hist tables
#define NB_HIST 256           // hist blocks (slice 6250)
#define NB_BIN  256           // bin blocks (slice 6250, same rows as hist)
#define DCAP    1536          // fixed dump capacity per bucket (max ~1136 + 12 sigma)

// ws layout (bytes)
#define OFF_BTOT   0x1000u     // int[NBUCK_P] bucket totals (record count m)
#define OFF_HS     0x780000u   // fp8[N_NODES*128] (12.8 MB)
#define OFF_WT     0x2100000u  // __half[128*128] fp16 W1^T (32 KB)
#define OFF_WLT    0x2110000u  // __half[64*128]  fp16 linW^T, class-padded (16 KB)
#define OFF_GHIST  0x3980000u  // int[NB_HIST*NBUCK_P]  (1.6 MB)
#define OFF_GCHOFF 0x3B10000u  // int[NB_BIN*NBUCK_P]   (1.6 MB)
#define OFF_DUMP   0x3CA0000u  // int[NBUCK*DCAP] packed (9.6 MB)

typedef _Float16 half8_t __attribute__((ext_vector_type(8)));
typedef float f32x2_t __attribute__((ext_vector_type(2)));
typedef float f32x4_t __attribute__((ext_vector_type(4)));
typedef float f32x16_t __attribute__((ext_vector_type(16)));

// blocks [0,255]: per-block bucket histogram of dst (inline dtype detect).
// blocks [256,271]: W1 (f32 [128k][128n]) -> Wt fp16 [128n][128k].
// block  272:       linW (f32 [128k][40c]) -> WlT fp16 [64c][128k] (pad c>=40 = 0).
__global__ __launch_bounds__(256) void k_hist(const int* __restrict__ p32,
                                              int* __restrict__ G_hist,
                                              const float* __restrict__ W,
                                              __half* __restrict__ Wt,
                                              const float* __restrict__ linW,
                                              __half* __restrict__ WlT) {
  const int t = threadIdx.x;
  if (blockIdx.x == NB_HIST + 16) {  // ---- linW transpose ----
    __shared__ float buf[5120];
#pragma unroll
    for (int i = 0; i < 5; ++i) {
      int lin = i * 256 + t;
      ((float4*)buf)[lin] = ((const float4*)linW)[lin];
    }
    __syncthreads();
#pragma unroll
    for (int i = 0; i < 4; ++i) {
      int lin = i * 256 + t;  // 1024 int4s = 64 rows x 16
      int c = lin >> 4, kb = lin & 15;
      union { __half h[8]; int4 v; } u;
#pragma unroll
      for (int q = 0; q < 8; ++q)
        u.h[q] = (c < 40) ? __float2half(buf[(kb * 8 + q) * 40 + c])
                          : __float2half(0.f);
      *(int4*)&WlT[(size_t)c * 128 + kb * 8] = u.v;
    }
    return;
  }
  if (blockIdx.x >= NB_HIST) {  // ---- W1 transpose ----
    __shared__ float buf1[1024];
    const int b = blockIdx.x - NB_HIST;
    float4 v = ((const float4*)(W + (size_t)b * 1024))[t];
    *(float4*)&buf1[t * 4] = v;
    __syncthreads();
    if (t < 128) {
      union { __half h[8]; int4 v; } u;
#pragma unroll
      for (int k = 0; k < 8; ++k) u.h[k] = __float2half(buf1[k * 128 + t]);
      *(int4*)&Wt[(size_t)t * 128 + b * 8] = u.v;
    }
    return;
  }
  __shared__ int hist[NBUCK];
  __shared__ int nz;
  if (t == 0) nz = 0;
  for (int i = t; i < NBUCK; i += 256) hist[i] = 0;
  __syncthreads();
  if (p32[2 * t + 1] != 0) atomicAdd(&nz, 1);
  __syncthreads();
  const int s = (nz == 0) ? 1 : 0;  // 1 => int64 (stride 2)
  const int base = blockIdx.x * 6250;
  for (int i = 0; i < 25; ++i) {
    int e = base + i * 256 + t;
    if (e < base + 6250) {
      int c = p32[((size_t)(N_EDGES + e)) << s];
      atomicAdd(&hist[c >> 6], 1);
    }
  }
  __syncthreads();
  for (int i = t; i < NBUCK; i += 256) G_hist[blockIdx.x * NBUCK_P + i] = hist[i];
}

// per bucket: scan 256 exact chunk sizes -> per-binblock offsets + total (= m)
__global__ __launch_bounds__(256) void k_bucket_scan(const int* __restrict__ G_hist,
                                                     int* __restrict__ G_choff,
                                                     int* __restrict__ btot) {
  __shared__ int wsum[4];
  const int t = threadIdx.x;
  const int b = blockIdx.x;
  const int c = G_hist[t * NBUCK_P + b];
  int sv = c;
  const int lane = t & 63;
  for (int d = 1; d < 64; d <<= 1) {
    int a = __shfl_up(sv, d);
    if (lane >= d) sv += a;
  }
  if (lane == 63) wsum[t >> 6] = sv;
  __syncthreads();
  int o = 0;
  for (int w2 = 0; w2 < (t >> 6); ++w2) o += wsum[w2];
  G_choff[t * NBUCK_P + b] = o + sv - c;  // exclusive offset within bucket
  if (t == 255) btot[b] = o + sv;
}

// place packed (src<<6|ldst) records into block-private chunks at fixed bases
__global__ __launch_bounds__(512) void k_bin(const int* __restrict__ p32,
                                             const int* __restrict__ G_choff,
                                             int* __restrict__ dump) {
  __shared__ int gb[NBUCK];
  __shared__ int cur[NBUCK];
  __shared__ int nz;
  const int t = threadIdx.x;
  const int blk = blockIdx.x;
  if (t == 0) nz = 0;
  for (int i = t; i < NBUCK; i += 512) {
    gb[i] = i * DCAP + G_choff[blk * NBUCK_P + i];
    cur[i] = 0;
  }
  __syncthreads();
  if (t < 256 && p32[2 * t + 1] != 0) atomicAdd(&nz, 1);
  __syncthreads();
  const int s = (nz == 0) ? 1 : 0;
  const int base = blk * 6250;
  for (int i = 0; i < 13; ++i) {
    int e = base + i * 512 + t;
    if (e < base + 6250) {
      int r = p32[((size_t)e) << s];
      int c = p32[((size_t)(N_EDGES + e)) << s];
      int bk = c >> 6;
      int p = atomicAdd(&cur[bk], 1);
      dump[gb[bk] + p] = (r << 6) | (c & 63);
    }
  }
}

// hs[n] = fp8_e4m3( rsqrt(deg[n]+1) * (x @ W1)[n] )  via MFMA f16.
// deg computed in-block from this bucket's dump chunk (block b == bucket b).
__global__ __launch_bounds__(256, 3) void k_gemm1(
    const float* __restrict__ x, const __half* __restrict__ Wt,
    const int* __restrict__ dump, const int* __restrict__ btot,
    unsigned char* __restrict__ hs8) {
  __shared__ _Float16 xt[64 * 136];
  __shared__ _Float16 wt[128 * 136];
  __shared__ int c_s[64];
  const int t = threadIdx.x;
  const int b = blockIdx.x;
  const int row0 = b * 64;
  if (t < 64) c_s[t] = 0;
  __syncthreads();
#pragma unroll
  for (int i = 0; i < 8; ++i) {
    int lin = i * 256 + t;
    int r = lin >> 5, c4 = lin & 31;
    int gr = row0 + r;
    float4 v = make_float4(0.f, 0.f, 0.f, 0.f);
    if (gr < N_NODES) v = *(const float4*)(x + (size_t)gr * 128 + c4 * 4);
    union { __half2 h2[2]; int2 iv; } u;
    u.h2[0] = __floats2half2_rn(v.x, v.y);
    u.h2[1] = __floats2half2_rn(v.z, v.w);
    *(int2*)&xt[r * 136 + c4 * 4] = u.iv;
  }
#pragma unroll
  for (int i = 0; i < 8; ++i) {
    int lin = i * 256 + t;
    int n = lin >> 4, kb = lin & 15;
    int4 v = *(const int4*)(Wt + (size_t)n * 128 + kb * 8);
    *(int4*)&wt[n * 136 + kb * 8] = v;
  }
  {
    const int rb = b * DCAP;
    const int m = btot[b];
    for (int j = t; j < m; j += 256) atomicAdd(&c_s[dump[rb + j] & 63], 1);
  }
  __syncthreads();

  const int w = t >> 6, l = t & 63;
  const int r = l & 15, g = l >> 4;
  const _Float16* ap = &xt[(w * 16 + r) * 136 + g * 8];
  half8_t af[4];
#pragma unroll
  for (int ks = 0; ks < 4; ++ks) af[ks] = *(const half8_t*)&ap[ks * 32];

  const int lbase = w * 16 + g * 4;
  const int rbase = row0 + lbase;
  float dv[4];
#pragma unroll
  for (int j = 0; j < 4; ++j)
    dv[j] = rsqrtf((float)c_s[lbase + j] + 1.0f);

#pragma unroll
  for (int ct = 0; ct < 8; ++ct) {
    f32x4_t acc = {0.f, 0.f, 0.f, 0.f};
    const _Float16* bp = &wt[(ct * 16 + r) * 136 + g * 8];
#pragma unroll
    for (int ks = 0; ks < 4; ++ks) {
      half8_t bf = *(const half8_t*)&bp[ks * 32];
      acc = __builtin_amdgcn_mfma_f32_16x16x32_f16(af[ks], bf, acc, 0, 0, 0);
    }
#pragma unroll
    for (int j = 0; j < 4; ++j) {
      int rr = rbase + j;
      if (rr < N_NODES) {
        unsigned int pk =
            __builtin_amdgcn_cvt_pk_fp8_f32(acc[j] * dv[j], 0.f, 0u, false);
        hs8[(size_t)rr * 128 + ct * 16 + r] = (unsigned char)(pk & 0xffu);
      }
    }
  }
}

// fully fused per bucket (64 nodes, 512 threads):
// local deg + CSR placement -> fp8 gather-aggregate (f32x4 pk_add accum) ->
// relu'd fp16 rows in LDS -> MFMA Linear -> log_softmax -> out.
__global__ __launch_bounds__(512, 8) void k_aggfin(
    const unsigned char* __restrict__ hs8, const int* __restrict__ dump,
    const int* __restrict__ btot, const float* __restrict__ b1,
    const __half* __restrict__ WlT, const float* __restrict__ linb,
    float* __restrict__ out) {
  __shared__ int stage[4352];          // 17408 B; alias vs[64][136] f16, outbuf[64][68] f32
  __shared__ _Float16 wlt[64 * 136];   // 17408 B
  __shared__ float lb_s[64];
  __shared__ int cnt_s[64];
  __shared__ int off_s[64];
  __shared__ int cur_s[64];
  _Float16* vs = (_Float16*)stage;
  float* outbuf = (float*)stage;

  const int t = threadIdx.x;
  const int b = blockIdx.x;
  const int n0 = b << 6;
  if (t < 64) cnt_s[t] = 0;
#pragma unroll
  for (int i = 0; i < 2; ++i) {
    int lin = i * 512 + t;  // 1024 int4s = 64 rows x 16
    int c = lin >> 4, kb = lin & 15;
    int4 v = *(const int4*)(WlT + (size_t)c * 128 + kb * 8);
    *(int4*)&wlt[c * 136 + kb * 8] = v;
  }
  if (t < 64) lb_s[t] = (t < 40) ? linb[t] : 0.f;
  __syncthreads();

  const int rb = b * DCAP;
  const int m = btot[b];
  // pass 1: degree count
  for (int j = t; j < m; j += 512) atomicAdd(&cnt_s[dump[rb + j] & 63], 1);
  __syncthreads();
  if (t < 64) {
    int v = cnt_s[t];
    int sv = v;
    for (int d = 1; d < 64; d <<= 1) {
      int u = __shfl_up(sv, d);
      if (t >= d) sv += u;
    }
    off_s[t] = sv - v;
    cur_s[t] = sv - v;
  }
  __syncthreads();
  // pass 2: place src indices grouped by dst
  for (int j = t; j < m; j += 512) {
    int rec = dump[rb + j];
    int p = atomicAdd(&cur_s[rec & 63], 1);
    stage[p] = rec >> 6;
  }
  __syncthreads();

  // gather-aggregate: half-wave hw handles nodes hw, hw+16, hw+32, hw+48.
  // Each lane owns cols lane*4..lane*4+3 (4 fp8 bytes = 1 dword per row).
  const int hw = t >> 5, lane = t & 31;
  uint2 res[4];
#pragma unroll
  for (int mi = 0; mi < 4; ++mi) {
    res[mi] = make_uint2(0u, 0u);
    const int i = hw + mi * 16;
    const int n = n0 + i;
    if (n >= N_NODES) continue;
    f32x4_t sum;
    {
      unsigned int raw = *(const unsigned int*)(hs8 + (size_t)n * 128 + lane * 4);
      f32x2_t lo = __builtin_amdgcn_cvt_pk_f32_fp8(raw, false);
      f32x2_t hi = __builtin_amdgcn_cvt_pk_f32_fp8(raw, true);
      sum[0] = lo[0]; sum[1] = lo[1]; sum[2] = hi[0]; sum[3] = hi[1];  // self-loop
    }
    int j = off_s[i];
    const int e0 = off_s[i] + cnt_s[i];
    for (; j + 8 <= e0; j += 8) {
      unsigned int r[8];
#pragma unroll
      for (int q = 0; q < 8; ++q) {
        int src = stage[j + q];
        r[q] = *(const unsigned int*)(hs8 + (size_t)src * 128 + lane * 4);
      }
#pragma unroll
      for (int q = 0; q < 8; ++q) {
        f32x2_t lo = __builtin_amdgcn_cvt_pk_f32_fp8(r[q], false);
        f32x2_t hi = __builtin_amdgcn_cvt_pk_f32_fp8(r[q], true);
        f32x4_t v; v[0] = lo[0]; v[1] = lo[1]; v[2] = hi[0]; v[3] = hi[1];
        sum += v;  // v_pk_add_f32 x2
      }
    }
    if (j + 4 <= e0) {
      unsigned int r[4];
#pragma unroll
      for (int q = 0; q < 4; ++q) {
        int src = stage[j + q];
        r[q] = *(const unsigned int*)(hs8 + (size_t)src * 128 + lane * 4);
      }
#pragma unroll
      for (int q = 0; q < 4; ++q) {
        f32x2_t lo = __builtin_amdgcn_cvt_pk_f32_fp8(r[q], false);
        f32x2_t hi = __builtin_amdgcn_cvt_pk_f32_fp8(r[q], true);
        f32x4_t v; v[0] = lo[0]; v[1] = lo[1]; v[2] = hi[0]; v[3] = hi[1];
        sum += v;
      }
      j += 4;
    }
    for (; j < e0; ++j) {
      int src = stage[j];
      unsigned int raw = *(const unsigned int*)(hs8 + (size_t)src * 128 + lane * 4);
      f32x2_t lo = __builtin_amdgcn_cvt_pk_f32_fp8(raw, false);
      f32x2_t hi = __builtin_amdgcn_cvt_pk_f32_fp8(raw, true);
      f32x4_t v; v[0] = lo[0]; v[1] = lo[1]; v[2] = hi[0]; v[3] = hi[1];
      sum += v;
    }
    float d = rsqrtf((float)cnt_s[i] + 1.0f);
    float4 bb = *(const float4*)(b1 + lane * 4);
    union { __half2 h[2]; uint2 v; } u;
    u.h[0] = __floats2half2_rn(fmaxf(fmaf(d, sum[0], bb.x), 0.f),
                               fmaxf(fmaf(d, sum[1], bb.y), 0.f));
    u.h[1] = __floats2half2_rn(fmaxf(fmaf(d, sum[2], bb.z), 0.f),
                               fmaxf(fmaf(d, sum[3], bb.w), 0.f));
    res[mi] = u.v;
  }
  __syncthreads();  // stage (records) dead -> reuse as vs
#pragma unroll
  for (int mi = 0; mi < 4; ++mi) {
    const int i = hw + mi * 16;
    *(uint2*)&vs[i * 136 + lane * 4] = res[mi];
  }
  __syncthreads();

  // MFMA Linear: vs[64x128] @ wlt^T -> logits 64x64 (cols>=40 ignored).
  const int wv = t >> 6, l64 = t & 63;
  f32x16_t C = {};
  int colg = 0, lbv_valid = 0;
  float lbv = 0.f;
  if (wv < 4) {
    const int rowt = wv >> 1, colt = wv & 1;
    const int rw = l64 & 31, kg = l64 >> 5;  // kg in {0,1}
    const _Float16* ap = &vs[(rowt * 32 + rw) * 136 + kg * 8];
    const _Float16* bp = &wlt[(colt * 32 + rw) * 136 + kg * 8];
#pragma unroll
    for (int ks = 0; ks < 8; ++ks) {
      half8_t af = *(const half8_t*)&ap[ks * 16];
      half8_t bf = *(const half8_t*)&bp[ks * 16];
      C = __builtin_amdgcn_mfma_f32_32x32x16_f16(af, bf, C, 0, 0, 0);
    }
    colg = colt * 32 + rw;
    lbv = lb_s[colg];
    lbv_valid = 1;
  }
  __syncthreads();  // all vs reads done -> safe to overwrite as outbuf
  if (lbv_valid && colg < 40) {
    const int rowt = (t >> 6) >> 1;
    const int hi = (t & 63) >> 5;
#pragma unroll
    for (int q = 0; q < 16; ++q) {
      int row = (q & 3) + 8 * (q >> 2) + 4 * hi;  // C/D layout (m74/m101)
      outbuf[(rowt * 32 + row) * 68 + colg] = C[q] + lbv;
    }
  }
  __syncthreads();

  // softmax: node = t>>3, 5 classes per lane
  const int node = t >> 3;
  const int cg = (t & 7) * 5;
  const int n = n0 + node;
  float lg[5];
#pragma unroll
  for (int j = 0; j < 5; ++j) lg[j] = outbuf[node * 68 + cg + j];
  float mx = lg[0];
#pragma unroll
  for (int j = 1; j < 5; ++j) mx = fmaxf(mx, lg[j]);
  mx = fmaxf(mx, __shfl_xor(mx, 1));
  mx = fmaxf(mx, __shfl_xor(mx, 2));
  mx = fmaxf(mx, __shfl_xor(mx, 4));
  float ssum = 0.f;
#pragma unroll
  for (int j = 0; j < 5; ++j) ssum += expf(lg[j] - mx);
  ssum += __shfl_xor(ssum, 1);
  ssum += __shfl_xor(ssum, 2);
  ssum += __shfl_xor(ssum, 4);
  float lse = mx + logf(ssum);
  if (n < N_NODES) {
#pragma unroll
    for (int j = 0; j < 5; ++j) out[(size_t)n * 40 + cg + j] = lg[j] - lse;
  }
}

extern "C" void kernel_launch(void* const* d_in, const int* in_sizes, int n_in,
                              void* d_out, int out_size, void* d_ws, size_t ws_size,
                              hipStream_t stream) {
  const float* x    = (const float*)d_in[0];
  const int*   ei   = (const int*)d_in[1];
  const float* W1   = (const float*)d_in[2];
  const float* b1   = (const float*)d_in[3];
  const float* linW = (const float*)d_in[4];
  const float* linb = (const float*)d_in[5];
  float* out = (float*)d_out;
  char* ws = (char*)d_ws;

  int*           btot   = (int*)(ws + OFF_BTOT);
  unsigned char* hs8    = (unsigned char*)(ws + OFF_HS);
  __half*        Wt     = (__half*)(ws + OFF_WT);
  __half*        WlT    = (__half*)(ws + OFF_WLT);
  int*           ghist  = (int*)(ws + OFF_GHIST);
  int*           gchoff = (int*)(ws + OFF_GCHOFF);
  int*           dump   = (int*)(ws + OFF_DUMP);

  k_hist<<<NB_HIST + 17, 256, 0, stream>>>(ei, ghist, W1, Wt, linW, WlT);
  k_bucket_scan<<<NBUCK, 256, 0, stream>>>(ghist, gchoff, btot);
  k_bin<<<NB_BIN, 512, 0, stream>>>(ei, gchoff, dump);
  k_gemm1<<<NBUCK, 256, 0, stream>>>(x, Wt, dump, btot, hs8);
  k_aggfin<<<NBUCK, 512, 0, stream>>>(hs8, dump, btot, b1, WlT, linb, out);
}